// Round 8
// baseline (9756.444 us; speedup 1.0000x reference)
//
#include <hip/hip_runtime.h>
#include <math.h>

// DARTS recurrent cell on MI355X — persistent cooperative kernel, v8.
// v7 -> v8: barrier-surviving cross-unit weight pipeline.
//  - two persistent reg buffers wA/wB alternate across the 9 GEMM units;
//    loads issue right after the previous unit's publish, consumed a full
//    unit later (~2-4us flight vs 0.7us LLC latency).
//  - post-poll barriers: bare s_barrier (no vmcnt drain) so prefetches fly
//    across them; post-rwrite barriers: lgkmcnt(0)-only; full __syncthreads
//    kept ONLY before flag publishes (fstore drain).
//  - asm memory clobbers pin prefetch issue points (no compiler sinking).

typedef __attribute__((ext_vector_type(8))) _Float16 half8;
typedef __attribute__((ext_vector_type(4))) float f32x4;
typedef __attribute__((ext_vector_type(4))) unsigned int u32x4;
typedef __attribute__((ext_vector_type(8))) unsigned short us8;

#define NH 1024
#define SCALE 2048.f
#define INVS  (1.f/2048.f)
#define WF_BYTES 83886080ull
#define FA_BYTES 1572864ull
#define T_STEPS  256

// weak barrier: execution sync, NO vmcnt drain (prefetches survive)
#define WBAR() asm volatile("s_barrier" ::: "memory")
// LDS barrier: drain LDS ops only, then barrier
#define LBAR() asm volatile("s_waitcnt lgkmcnt(0)\n\ts_barrier" ::: "memory")

__device__ __forceinline__ float sigf(float x){ return 1.f/(1.f+__expf(-x)); }
__device__ __forceinline__ void limbs2(float x, _Float16& a, _Float16& b){
    a = (_Float16)x; b = (_Float16)((x - (float)a)*SCALE);
}

// ---------------- weight pre-swizzle (identical to v4-v7, proven) ------------
struct Pre { const float* W0; const float* Ws; unsigned short* wf; };

__global__ __launch_bounds__(256) void preconv(Pre d) {
    int gid  = blockIdx.x * 4 + (threadIdx.x >> 6);
    int lane = threadIdx.x & 63;
    const float* W; unsigned short* dst; int nks, cg, ks;
    if (gid < 8192) {
        W = d.W0; dst = d.wf; nks = 64; cg = gid >> 6; ks = gid & 63;
    } else {
        int g = gid - 8192; int mm = g >> 12; int wi = g & 4095;
        W   = d.Ws + (size_t)mm * (1024 * 2048);
        dst = d.wf + 8388608ull + (size_t)mm * 4194304ull;
        nks = 32; cg = wi >> 5; ks = wi & 31;
    }
    int c  = cg * 16 + (lane & 15);
    int kb = ks * 32 + (lane >> 4) * 8;
    half8 h0, h1;
    #pragma unroll
    for (int j = 0; j < 8; ++j) {
        _Float16 p, q; limbs2(W[(size_t)(kb + j) * 2048 + c], p, q);
        h0[j] = p; h1[j] = q;
    }
    unsigned short* o = dst + ((size_t)cg * nks + ks) * 1024 + lane * 8;
    *(half8*)o         = h0;
    *(half8*)(o + 512) = h1;
}

// -------- init: hidden -> interleaved H frag plane; flag init ----------------
__global__ __launch_bounds__(256) void initk(const float* hidden, char* fa, unsigned* flags) {
    int gid = blockIdx.x * 256 + threadIdx.x;
    if (gid < 1536) flags[gid] = (gid < 256) ? 1u : 0u;
    #pragma unroll
    for (int e = 0; e < 4; ++e) {
        int i = gid * 4 + e;
        int row = i >> 10, col = i & 1023;
        int rt = row >> 4, rowf = row & 15;
        int ksp = col >> 5, kin = col & 31;
        int lanep = (kin >> 3) * 16 + rowf;
        size_t off = (size_t)rt * 65536 + ((size_t)ksp * 64 + lanep) * 32 + (kin & 7) * 4;
        _Float16 u0, u1; limbs2(hidden[i], u0, u1);
        unsigned pk = (unsigned)__builtin_bit_cast(unsigned short, u0) |
                      ((unsigned)__builtin_bit_cast(unsigned short, u1) << 16);
        *(unsigned*)(fa + off) = pk;
    }
}

// ------------------------------ device helpers -------------------------------
__device__ __forceinline__ void aload(const char* fa, int ks, int lane, half8& a0, half8& a1) {
    const char* p = fa + ((size_t)ks * 64 + lane) * 32;
    us8 q0 = *(const us8*)p;
    us8 q1 = *(const us8*)(p + 16);
    a0 = __builtin_bit_cast(half8, __builtin_shufflevector(q0, q1, 0,2,4,6,8,10,12,14));
    a1 = __builtin_bit_cast(half8, __builtin_shufflevector(q0, q1, 1,3,5,7,9,11,13,15));
}
__device__ __forceinline__ half8 ldw(const unsigned short* p) { return *(const half8*)p; }
__device__ __forceinline__ void mfma6(half8 a0, half8 a1, half8 w0, half8 w1,
                                      f32x4& x0, f32x4& x1) {
    x0 = __builtin_amdgcn_mfma_f32_16x16x32_f16(a0, w0, x0, 0, 0, 0);
    x1 = __builtin_amdgcn_mfma_f32_16x16x32_f16(a0, w1, x1, 0, 0, 0);
    x1 = __builtin_amdgcn_mfma_f32_16x16x32_f16(a1, w0, x1, 0, 0, 0);
}
__device__ __forceinline__ void rwrite1(float* arena, int wave, int lane,
        f32x4 c0, f32x4 c1, f32x4 h0, f32x4 h1) {
    float* b = arena + wave * 512;
    #pragma unroll
    for (int r = 0; r < 4; ++r) {
        b[lane * 4 + r]       = c0[r] + c1[r] * INVS;
        b[256 + lane * 4 + r] = h0[r] + h1[r] * INVS;
    }
}
__device__ __forceinline__ void rsum1(const float* arena, int idx, float& cs, float& hs) {
    float c = 0.f, h = 0.f;
    #pragma unroll
    for (int w = 0; w < 8; ++w) {
        c += arena[w * 512 + idx];
        h += arena[w * 512 + 256 + idx];
    }
    cs = c; hs = h;
}
__device__ __forceinline__ void fstore(char* fa, int offp, float v) {
    _Float16 u0, u1; limbs2(v, u0, u1);
    unsigned pk = (unsigned)__builtin_bit_cast(unsigned short, u0) |
                  ((unsigned)__builtin_bit_cast(unsigned short, u1) << 16);
    __hip_atomic_store((unsigned*)(fa + offp), pk, __ATOMIC_RELAXED, __HIP_MEMORY_SCOPE_AGENT);
}
template<int ACQ>
__device__ __forceinline__ void pollw(unsigned* f, unsigned tgt, int lane) {
    unsigned v = __hip_atomic_load(f + lane, __ATOMIC_RELAXED, __HIP_MEMORY_SCOPE_AGENT);
    while (__ballot(v < tgt)) {
        __builtin_amdgcn_s_sleep(2);
        v = __hip_atomic_load(f + lane, __ATOMIC_RELAXED, __HIP_MEMORY_SCOPE_AGENT);
    }
    if (ACQ)
        (void)__hip_atomic_load(f, __ATOMIC_ACQUIRE, __HIP_MEMORY_SCOPE_AGENT);
}
__device__ __forceinline__ void publish(unsigned* slot, unsigned v) {
    __hip_atomic_store(slot, v, __ATOMIC_RELAXED, __HIP_MEMORY_SCOPE_AGENT);
}

// ------------------------------ persistent kernel ----------------------------
struct PK {
    const float* x; const float* hidden;
    const unsigned short* wf;
    char* fa; unsigned* flags; float* out;
};

__global__ __launch_bounds__(512, 2) void persist(PK p) {
    __shared__ unsigned short slab[65536];   // 128 KB: W0h frags
    __shared__ float arena[4096];            // 16 KB reduce arena

    const int tid  = threadIdx.x;
    const int wave = tid >> 6, lane = tid & 63;
    const int l15 = lane & 15, lg = lane >> 4;
    const int lane8 = lane * 8, lg8 = lg * 8;
    const int bx = blockIdx.x;
    const int cg = (bx & 7) * 8 + ((bx >> 3) & 7);
    const int rt = bx >> 6;

    const unsigned short* wf0 = p.wf;
    const unsigned short* wfs[8];
    #pragma unroll
    for (int i = 0; i < 8; ++i) wfs[i] = p.wf + 8388608ull + (size_t)i * 4194304ull;

    char* FAH  = p.fa + (size_t)(0 * 4 + rt) * 65536;
    char* FAS0 = p.fa + (size_t)(1 * 4 + rt) * 65536;
    char* FAS1 = p.fa + (size_t)(2 * 4 + rt) * 65536;
    char* FAS2 = p.fa + (size_t)(3 * 4 + rt) * 65536;
    char* FAS3 = p.fa + (size_t)(4 * 4 + rt) * 65536;
    char* FAS5 = p.fa + (size_t)(5 * 4 + rt) * 65536;
    #define FLG(tn) (p.flags + ((tn) * 4 + rt) * 64)

    // 16 frags of one Ws matrix (this wave's 4 ks) into a named buffer
    #define PFW(dst, wfp) do { \
        _Pragma("unroll") \
        for (int _i = 0; _i < 4; ++_i) { \
            const int _ks = wave * 4 + _i; \
            const unsigned short* _pc = (wfp) + ((size_t)cg * 32 + _ks) * 1024 + lane8; \
            const unsigned short* _ph = (wfp) + ((size_t)(cg + 64) * 32 + _ks) * 1024 + lane8; \
            dst[_i*4+0] = ldw(_pc); dst[_i*4+1] = ldw(_pc + 512); \
            dst[_i*4+2] = ldw(_ph); dst[_i*4+3] = ldw(_ph + 512); } } while (0)
    // W0 x-part frags (ks 0..31 of nks=64)
    #define PFWX(dst) do { \
        _Pragma("unroll") \
        for (int _i = 0; _i < 4; ++_i) { \
            const int _ks = wave * 4 + _i; \
            const unsigned short* _pc = wf0 + ((size_t)cg * 64 + _ks) * 1024 + lane8; \
            const unsigned short* _ph = wf0 + ((size_t)(cg + 64) * 64 + _ks) * 1024 + lane8; \
            dst[_i*4+0] = ldw(_pc); dst[_i*4+1] = ldw(_pc + 512); \
            dst[_i*4+2] = ldw(_ph); dst[_i*4+3] = ldw(_ph + 512); } } while (0)
    #define ALD(dst0, dst1, fa) do { \
        _Pragma("unroll") \
        for (int _i = 0; _i < 4; ++_i) aload(fa, wave * 4 + _i, lane, dst0[_i], dst1[_i]); } while (0)
    #define MFM(w, a0v, a1v, X0, X1, Y0, Y1) do { \
        _Pragma("unroll") \
        for (int _i = 0; _i < 4; ++_i) { \
            mfma6(a0v[_i], a1v[_i], w[_i*4+0], w[_i*4+1], X0, X1); \
            mfma6(a0v[_i], a1v[_i], w[_i*4+2], w[_i*4+3], Y0, Y1); } } while (0)

    // ---- fill W0h LDS slab (once) ----
    {
        const u32x4* sc = (const u32x4*)(wf0 + ((size_t)cg * 64 + 32) * 1024);
        const u32x4* sh = (const u32x4*)(wf0 + ((size_t)(cg + 64) * 64 + 32) * 1024);
        u32x4* dst = (u32x4*)slab;
        for (int i = tid; i < 4096; i += 512) { dst[i] = sc[i]; dst[4096 + i] = sh[i]; }
    }

    const int rowf = tid >> 4, colf = tid & 15;
    const size_t opos = (size_t)(rt * 16 + rowf) * NH + cg * 16 + colf;
    const int idx = colf * 4 + (rowf >> 2) * 64 + (rowf & 3);
    int offp;
    {
        int col = cg * 16 + colf;
        int ksp = col >> 5, kin = col & 31;
        int lanep = (kin >> 3) * 16 + rowf;
        offp = (ksp * 64 + lanep) * 32 + (kin & 7) * 4;
    }
    float hprev = 0.f, s0v = 0.f, s1v = 0.f, s2v = 0.f, s3v = 0.f, s5v = 0.f, runsum = 0.f;
    if (tid < 256) hprev = p.hidden[opos];
    const int xrow = rt * 16 + l15;
    __syncthreads();

    // persistent stream buffers; pre-loop fill for t=0
    half8 wA[16], wB[16];
    PFW(wA, wfs[0]);     // Ws0 -> u1
    PFWX(wB);            // W0x -> L1

    for (int t = 0; t < T_STEPS; ++t) {
        const float* xt = p.x + (size_t)t * 65536;

        // ========== L1: x-part (wB=W0x), poll H under it; h-part from slab ===
        f32x4 c0 = {}, c1 = {}, h0 = {}, h1 = {};
        {
            half8 xa0[4], xa1[4];
            #pragma unroll
            for (int i = 0; i < 4; ++i) {
                const int ks = wave * 4 + i;
                const float* xp = xt + (size_t)xrow * NH + ks * 32 + lg8;
                float4 v0 = *(const float4*)xp, v1 = *(const float4*)(xp + 4);
                float fv[8] = {v0.x, v0.y, v0.z, v0.w, v1.x, v1.y, v1.z, v1.w};
                #pragma unroll
                for (int j = 0; j < 8; ++j) { _Float16 u, w2; limbs2(fv[j], u, w2); xa0[i][j] = u; xa1[i][j] = w2; }
            }
            if (wave == 7) {
                pollw<1>(FLG(0), t + 1, lane);               // the step's ONE acquire
                asm volatile("s_waitcnt vmcnt(0)" ::: "memory");
            }
            MFM(wB, xa0, xa1, c0, c1, h0, h1);
        }
        WBAR();                                              // gate FAH reads; no drain
        {
            half8 ha0[4], ha1[4];
            ALD(ha0, ha1, FAH);
            #pragma unroll
            for (int i = 0; i < 4; ++i) {
                const int kc = wave * 4 + i;
                const unsigned short* pc = &slab[kc * 1024 + lane8];
                const unsigned short* ph = &slab[(kc + 32) * 1024 + lane8];
                mfma6(ha0[i], ha1[i], *(const half8*)pc, *(const half8*)(pc + 512), c0, c1);
                mfma6(ha0[i], ha1[i], *(const half8*)ph, *(const half8*)(ph + 512), h0, h1);
            }
            rwrite1(arena, wave, lane, c0, c1, h0, h1);
        }
        LBAR();
        if (tid < 256) {
            float cs, hs; rsum1(arena, idx, cs, hs);
            s0v = hprev + sigf(cs) * (tanhf(hs) - hprev);
            fstore(FAS0, offp, s0v);
        }
        __syncthreads();
        if (tid == 0) publish(FLG(1) + cg, t + 1);
        PFW(wB, wfs[1]);                                     // Ws1 -> u2

        // ========== u1/L2: s1 (wA=Ws0) =======================================
        if (wave == 7) pollw<0>(FLG(1), t + 1, lane);
        WBAR();
        half8 a0[4], a1[4];
        {
            ALD(a0, a1, FAS0);
            f32x4 X0 = {}, X1 = {}, Y0 = {}, Y1 = {};
            MFM(wA, a0, a1, X0, X1, Y0, Y1);
            rwrite1(arena, wave, lane, X0, X1, Y0, Y1);
        }
        LBAR();
        if (tid < 256) {
            float cs, hs; rsum1(arena, idx, cs, hs);
            s1v = s0v + sigf(cs) * (sigf(hs) - s0v);
            fstore(FAS1, offp, s1v);
            runsum = s1v;
        }
        __syncthreads();
        if (tid == 0) publish(FLG(2) + cg, t + 1);
        PFW(wA, wfs[2]);                                     // Ws2 -> u3

        // ========== L3: s2 (wB=Ws1), s3 (wA=Ws2), s4 (wB=Ws3) ================
        if (wave == 7) pollw<0>(FLG(2), t + 1, lane);
        WBAR();
        ALD(a0, a1, FAS1);                                   // live through u4
        {
            f32x4 X0 = {}, X1 = {}, Y0 = {}, Y1 = {};
            MFM(wB, a0, a1, X0, X1, Y0, Y1);                 // u2: Ws1
            rwrite1(arena, wave, lane, X0, X1, Y0, Y1);
        }
        LBAR();
        if (tid < 256) {
            float cs, hs; rsum1(arena, idx, cs, hs);
            s2v = s1v + sigf(cs) * (fmaxf(hs, 0.f) - s1v);
            fstore(FAS2, offp, s2v);
        }
        __syncthreads();
        if (tid == 0) publish(FLG(3) + cg, t + 1);
        PFW(wB, wfs[3]);                                     // Ws3 -> u4
        {
            f32x4 X0 = {}, X1 = {}, Y0 = {}, Y1 = {};
            MFM(wA, a0, a1, X0, X1, Y0, Y1);                 // u3: Ws2
            rwrite1(arena, wave, lane, X0, X1, Y0, Y1);
        }
        LBAR();
        if (tid < 256) {
            float cs, hs; rsum1(arena, idx, cs, hs);
            s3v = s1v + sigf(cs) * (fmaxf(hs, 0.f) - s1v);
            fstore(FAS3, offp, s3v);
        }
        __syncthreads();
        if (tid == 0) publish(FLG(4) + cg, t + 1);
        PFW(wA, wfs[4]);                                     // Ws4 -> u5
        {
            f32x4 X0 = {}, X1 = {}, Y0 = {}, Y1 = {};
            MFM(wB, a0, a1, X0, X1, Y0, Y1);                 // u4: Ws3
            rwrite1(arena, wave, lane, X0, X1, Y0, Y1);
        }
        LBAR();
        if (tid < 256) {
            float cs, hs; rsum1(arena, idx, cs, hs);
            float s4v = s1v + sigf(cs) * (hs - s1v);
            runsum += s2v + s3v + s4v;
        }
        WBAR();
        PFW(wB, wfs[6]);                                     // Ws6 -> u6

        // ========== L4: s5 (wA=Ws4, A=s2), s7 (wB=Ws6, A=s3) =================
        if (wave == 7) { pollw<0>(FLG(3), t + 1, lane); pollw<0>(FLG(4), t + 1, lane); }
        WBAR();
        {
            half8 b0[4], b1[4];
            ALD(a0, a1, FAS2);
            ALD(b0, b1, FAS3);
            f32x4 X0 = {}, X1 = {}, Y0 = {}, Y1 = {};
            MFM(wA, a0, a1, X0, X1, Y0, Y1);                 // u5: Ws4
            f32x4 U0 = {}, U1 = {}, V0 = {}, V1 = {};
            MFM(wB, b0, b1, U0, U1, V0, V1);                 // u6: Ws6
            rwrite1(arena, wave, lane, X0, X1, Y0, Y1);
            LBAR();
            if (tid < 256) {
                float cs, hs; rsum1(arena, idx, cs, hs);
                s5v = s2v + sigf(cs) * (tanhf(hs) - s2v);
                fstore(FAS5, offp, s5v);
            }
            __syncthreads();
            if (tid == 0) publish(FLG(5) + cg, t + 1);
            PFW(wA, wfs[5]);                                 // Ws5 -> u7
            rwrite1(arena, wave, lane, U0, U1, V0, V1);
            LBAR();
            if (tid < 256) {
                float cs, hs; rsum1(arena, idx, cs, hs);
                float s7v = s3v + sigf(cs) * (tanhf(hs) - s3v);
                runsum += s5v + s7v;
            }
            WBAR();
            PFW(wB, wfs[7]);                                 // Ws7 -> u8
        }

        // ========== L5: s6 (wA=Ws5), s8 (wB=Ws7) + mean -> out[t] ============
        if (wave == 7) pollw<0>(FLG(5), t + 1, lane);
        WBAR();
        {
            ALD(a0, a1, FAS5);
            f32x4 X0 = {}, X1 = {}, Y0 = {}, Y1 = {};
            MFM(wA, a0, a1, X0, X1, Y0, Y1);                 // u7: Ws5
            f32x4 U0 = {}, U1 = {}, V0 = {}, V1 = {};
            MFM(wB, a0, a1, U0, U1, V0, V1);                 // u8: Ws7
            rwrite1(arena, wave, lane, X0, X1, Y0, Y1);
            LBAR();
            float c6 = 0.f, h6 = 0.f;
            if (tid < 256) rsum1(arena, idx, c6, h6);
            LBAR();                                          // reads drained before reuse
            PFW(wA, wfs[0]);                                 // Ws0 -> next step u1
            rwrite1(arena, wave, lane, U0, U1, V0, V1);
            LBAR();
            if (tid < 256) {
                float c8, h8; rsum1(arena, idx, c8, h8);
                float s6 = s5v + sigf(c6) * (sigf(h6) - s5v);
                float s8 = s5v + sigf(c8) * (fmaxf(h8, 0.f) - s5v);
                float v = 0.125f * (runsum + s6 + s8);
                p.out[(size_t)t * 65536 + opos] = v;
                fstore(FAH, offp, v);
                hprev = v;
            }
            __syncthreads();
            if (tid == 0) publish(FLG(0) + cg, t + 2);
            PFWX(wB);                                        // W0x -> next step L1
        }
    }
    #undef FLG
    #undef PFW
    #undef PFWX
    #undef ALD
    #undef MFM
}

// ---------------------------------- host -------------------------------------
extern "C" void kernel_launch(void* const* d_in, const int* in_sizes, int n_in,
                              void* d_out, int out_size, void* d_ws, size_t ws_size,
                              hipStream_t stream) {
    (void)in_sizes; (void)n_in; (void)out_size; (void)ws_size;
    const float* inputs = (const float*)d_in[0];
    const float* hidden = (const float*)d_in[1];
    const float* W0     = (const float*)d_in[2];
    const float* Ws     = (const float*)d_in[3];
    float* out = (float*)d_out;

    char* base = (char*)d_ws;
    unsigned short* wf = (unsigned short*)base;
    char* fa = base + WF_BYTES;
    unsigned* flags = (unsigned*)(fa + FA_BYTES);

    initk<<<64, 256, 0, stream>>>(hidden, fa, flags);
    preconv<<<10240, 256, 0, stream>>>(Pre{W0, Ws, wf});

    PK pk{inputs, hidden, wf, fa, flags, out};
    void* args[] = {&pk};
    if (hipLaunchCooperativeKernel((void*)persist, dim3(256), dim3(512), args, 0, stream) != hipSuccess)
        persist<<<256, 512, 0, stream>>>(pk);
}